// Round 1
// baseline (14.684 us; speedup 1.0000x reference)
//
#include <hip/hip_runtime.h>

// ItemRegressionModel: out[b] = bu + b_item[t] + sum_k(w_jt*resid)/K
// u:(B) t:(B) rating:(USERS,ITEMS) qtus:(USERS,ITEMS,K) weight:(ITEMS,ITEMS)
// b_user:(USERS) b_item:(ITEMS)  -> out:(B) f32
// USERS=4000 ITEMS=2000 K=16 B=16384

constexpr int ITEMS = 2000;
constexpr int K     = 16;

__global__ __launch_bounds__(256) void item_reg_kernel(
    const int*   __restrict__ u,
    const int*   __restrict__ t,
    const float* __restrict__ rating,
    const int*   __restrict__ qtus,
    const float* __restrict__ weight,
    const float* __restrict__ b_user,
    const float* __restrict__ b_item,
    float*       __restrict__ out,
    int B)
{
    int tid = blockIdx.x * blockDim.x + threadIdx.x;
    int b = tid >> 4;   // output index: 16 lanes per output
    int k = tid & 15;   // neighbor index
    if (b >= B) return;

    int uu = u[b];
    int tt = t[b];

    // coalesced across the 16-lane group: consecutive k -> consecutive addresses
    size_t qbase = ((size_t)uu * ITEMS + (size_t)tt) * K;
    int j = qtus[qbase + k];

    float w  = weight[(size_t)j * ITEMS + (size_t)tt];  // gather: column tt
    float r  = rating[(size_t)uu * ITEMS + (size_t)j];  // gather: row uu
    float bu = b_user[uu];
    float bj = b_item[j];

    float p = w * (r - bu - bj);

    // butterfly reduce within each 16-lane group
    p += __shfl_xor(p, 1, 16);
    p += __shfl_xor(p, 2, 16);
    p += __shfl_xor(p, 4, 16);
    p += __shfl_xor(p, 8, 16);

    if (k == 0) {
        out[b] = bu + b_item[tt] + p * (1.0f / (float)K);
    }
}

extern "C" void kernel_launch(void* const* d_in, const int* in_sizes, int n_in,
                              void* d_out, int out_size, void* d_ws, size_t ws_size,
                              hipStream_t stream) {
    const int*   u      = (const int*)  d_in[0];
    const int*   t      = (const int*)  d_in[1];
    const float* rating = (const float*)d_in[2];
    const int*   qtus   = (const int*)  d_in[3];
    const float* weight = (const float*)d_in[4];
    const float* b_user = (const float*)d_in[5];
    const float* b_item = (const float*)d_in[6];
    float*       out    = (float*)      d_out;

    int B = in_sizes[0];                  // 16384
    int threads = B * K;                  // 262144
    int block = 256;
    int grid = (threads + block - 1) / block;  // 1024

    item_reg_kernel<<<grid, block, 0, stream>>>(u, t, rating, qtus, weight,
                                                b_user, b_item, out, B);
}

// Round 2
// 14.038 us; speedup vs baseline: 1.0460x; 1.0460x over previous
//
#include <hip/hip_runtime.h>

// ItemRegressionModel: out[b] = bu + b_item[t] + sum_k(w_jt*resid)/K
// u:(B) t:(B) rating:(USERS,ITEMS) qtus:(USERS,ITEMS,K) weight:(ITEMS,ITEMS)
// b_user:(USERS) b_item:(ITEMS)  -> out:(B) f32
// USERS=4000 ITEMS=2000 K=16 B=16384
//
// R1: gather-bound, ~25MB unique 64B lines cold per replay -> ~1.7 TB/s eff.
// This round: nontemporal loads on the low-reuse gathers (qtus/weight/rating)
// to skip cache allocation; tests whether L1/L2 thrash contributes or we're
// purely HBM-random-transaction bound.

constexpr int ITEMS = 2000;
constexpr int K     = 16;

__global__ __launch_bounds__(256) void item_reg_kernel(
    const int*   __restrict__ u,
    const int*   __restrict__ t,
    const float* __restrict__ rating,
    const int*   __restrict__ qtus,
    const float* __restrict__ weight,
    const float* __restrict__ b_user,
    const float* __restrict__ b_item,
    float*       __restrict__ out,
    int B)
{
    int tid = blockIdx.x * blockDim.x + threadIdx.x;
    int b = tid >> 4;   // output index: 16 lanes per output
    int k = tid & 15;   // neighbor index
    if (b >= B) return;

    int uu = u[b];
    int tt = t[b];

    // coalesced across the 16-lane group: one 64B line per group
    size_t qbase = ((size_t)uu * ITEMS + (size_t)tt) * K;
    int j = __builtin_nontemporal_load(&qtus[qbase + k]);

    // the two heavy random gathers: nontemporal (one 4B use per 64B line,
    // reuse factor ~1.6 -> not worth allocating)
    float w  = __builtin_nontemporal_load(&weight[(size_t)j * ITEMS + (size_t)tt]);
    float r  = __builtin_nontemporal_load(&rating[(size_t)uu * ITEMS + (size_t)j]);

    // tiny arrays (8-16KB): normal loads, let them stay cached
    float bu = b_user[uu];
    float bj = b_item[j];

    float p = w * (r - bu - bj);

    // butterfly reduce within each 16-lane group
    p += __shfl_xor(p, 1, 16);
    p += __shfl_xor(p, 2, 16);
    p += __shfl_xor(p, 4, 16);
    p += __shfl_xor(p, 8, 16);

    if (k == 0) {
        out[b] = bu + b_item[tt] + p * (1.0f / (float)K);
    }
}

extern "C" void kernel_launch(void* const* d_in, const int* in_sizes, int n_in,
                              void* d_out, int out_size, void* d_ws, size_t ws_size,
                              hipStream_t stream) {
    const int*   u      = (const int*)  d_in[0];
    const int*   t      = (const int*)  d_in[1];
    const float* rating = (const float*)d_in[2];
    const int*   qtus   = (const int*)  d_in[3];
    const float* weight = (const float*)d_in[4];
    const float* b_user = (const float*)d_in[5];
    const float* b_item = (const float*)d_in[6];
    float*       out    = (float*)      d_out;

    int B = in_sizes[0];                  // 16384
    int threads = B * K;                  // 262144
    int block = 256;
    int grid = (threads + block - 1) / block;  // 1024

    item_reg_kernel<<<grid, block, 0, stream>>>(u, t, rating, qtus, weight,
                                                b_user, b_item, out, B);
}